// Round 1
// baseline (393.294 us; speedup 1.0000x reference)
//
#include <hip/hip_runtime.h>
#include <stdint.h>

// ConvAttnLayer: B=16, L=512, J=4(head_in), O=4(head_out), D=E=64.
// out0 = mean_j softmax(X_j W_oj X_j^T / 8) X_j   [16,512,4,64]
// out1 = attn [4,4,16,512,512]  (268 MB fp32 -> kernel is HBM-write-bound)
//
// One fused kernel: grid 256 blocks (1/CU), 512 threads (8 waves), 156 KB LDS.
// block = (b, o, l-tile of 128 rows); loops j=0..3 internally, accumulating ctx.
// Plain bf16 MFMA (16x16x32): score-noise sigma ~0.002 rel, threshold is 2% rel.

typedef __bf16 bf16x8 __attribute__((ext_vector_type(8)));
typedef float  f32x4  __attribute__((ext_vector_type(4)));

// LDS map (bytes). XRM: X row-major bf16, XOR-swizzled cells (row stride 128 B).
// XCM: X col-major bf16 [64][520] (pad +8 -> stride 1040 B = 16B-aligned, bank-rotated).
// WT/QB (Q phase) alias ACH (C phase) -- phase-disjoint.
#define XRM_OFF 0         // 65536
#define XCM_OFF 65536     // 66560
#define WT_OFF  132096    // 9216   : W^T [64][72] bf16
#define QB_OFF  141312    // 18432  : per-wave Q bounce [16][72] bf16
#define ACH_OFF 132096    // 18432  : per-wave attn chunk [16][72] bf16
#define LDS_BYTES 159744

__device__ __forceinline__ unsigned short f2bf(float f) {
    unsigned int u = __builtin_bit_cast(unsigned int, f);
    u += 0x7fffu + ((u >> 16) & 1u);   // round-to-nearest-even (finite inputs)
    return (unsigned short)(u >> 16);
}

__global__ __launch_bounds__(512, 2) void convattn_kernel(
    const float* __restrict__ inp,   // [16,512,4,64]
    const float* __restrict__ Wg,    // [4,4,64,64]
    float* __restrict__ out)         // out0 (2097152) ++ attn (67108864)
{
    extern __shared__ __align__(16) char smem[];

    const int tid  = threadIdx.x;
    const int wave = tid >> 6;
    const int lane = tid & 63;
    const int g    = lane >> 4;   // MFMA k-group
    const int ln   = lane & 15;   // MFMA row/col within tile

    // XCD-friendly decode: same-b blocks share an XCD (bid == b mod 16 -> bid%8 const)
    const int bid = blockIdx.x;
    const int b  = bid & 15;
    const int o  = (bid >> 4) & 3;
    const int lt = bid >> 6;

    float* attn_out = out + (size_t)2097152;

    f32x4 acc_c[4];
    #pragma unroll
    for (int i = 0; i < 4; ++i) { f32x4 z = {0.f,0.f,0.f,0.f}; acc_c[i] = z; }

    for (int j = 0; j < 4; ++j) {
        __syncthreads();   // protect LDS reuse across j iterations

        // ---------------- stage X_j (both orientations) + W^T ----------------
        {
            const int mrow = tid >> 4;          // 0..31
            const int e0   = (tid & 15) << 2;   // 0,4,..,60
            #pragma unroll
            for (int it = 0; it < 16; ++it) {
                const int m = it * 32 + mrow;
                const float4 v = *(const float4*)(inp + (((size_t)b * 512 + m) * 4 + j) * 64 + e0);
                const unsigned short b0 = f2bf(v.x), b1 = f2bf(v.y),
                                     b2 = f2bf(v.z), b3 = f2bf(v.w);
                // row-major, swizzled 16B cells: cell = (e>>3) ^ (m&7)
                char* p = smem + XRM_OFF + m * 128 + (((e0 >> 3) ^ (m & 7)) * 16) + (e0 & 7) * 2;
                *(unsigned int*)(p)     = (unsigned int)b0 | ((unsigned int)b1 << 16);
                *(unsigned int*)(p + 4) = (unsigned int)b2 | ((unsigned int)b3 << 16);
                // col-major [d][m], stride 1040 B
                *(unsigned short*)(smem + XCM_OFF + (e0 + 0) * 1040 + m * 2) = b0;
                *(unsigned short*)(smem + XCM_OFF + (e0 + 1) * 1040 + m * 2) = b1;
                *(unsigned short*)(smem + XCM_OFF + (e0 + 2) * 1040 + m * 2) = b2;
                *(unsigned short*)(smem + XCM_OFF + (e0 + 3) * 1040 + m * 2) = b3;
            }
            #pragma unroll
            for (int it = 0; it < 2; ++it) {
                const int d = it * 32 + mrow;
                const float4 v = *(const float4*)(Wg + (((size_t)o * 4 + j) * 64 + d) * 64 + e0);
                *(unsigned short*)(smem + WT_OFF + (e0 + 0) * 144 + d * 2) = f2bf(v.x);
                *(unsigned short*)(smem + WT_OFF + (e0 + 1) * 144 + d * 2) = f2bf(v.y);
                *(unsigned short*)(smem + WT_OFF + (e0 + 2) * 144 + d * 2) = f2bf(v.z);
                *(unsigned short*)(smem + WT_OFF + (e0 + 3) * 144 + d * 2) = f2bf(v.w);
            }
        }
        __syncthreads();

        // ---------------- Q = X_tile * W  (16 rows per wave) ----------------
        {
            const int lr = lt * 128 + wave * 16 + ln;   // A row = lane&15
            const bf16x8 a0 = *(const bf16x8*)(smem + XRM_OFF + lr * 128 + (((0 + g) ^ (lr & 7)) * 16));
            const bf16x8 a1 = *(const bf16x8*)(smem + XRM_OFF + lr * 128 + (((4 + g) ^ (lr & 7)) * 16));
            char* qb = smem + QB_OFF + wave * 2304;
            #pragma unroll
            for (int et = 0; et < 4; ++et) {
                const int e = et * 16 + ln;             // B col = lane&15
                const bf16x8 bw0 = *(const bf16x8*)(smem + WT_OFF + e * 144 + g * 16);
                const bf16x8 bw1 = *(const bf16x8*)(smem + WT_OFF + e * 144 + 64 + g * 16);
                f32x4 t = {0.f,0.f,0.f,0.f};
                t = __builtin_amdgcn_mfma_f32_16x16x32_bf16(a0, bw0, t, 0, 0, 0);
                t = __builtin_amdgcn_mfma_f32_16x16x32_bf16(a1, bw1, t, 0, 0, 0);
                #pragma unroll
                for (int r = 0; r < 4; ++r)            // C/D row = g*4+r, col = ln
                    *(unsigned short*)(qb + (g * 4 + r) * 144 + e * 2) = f2bf(t[r]);
            }
        }
        __syncthreads();

        // A-frags (Q) for S, kept in registers across the whole m sweep
        bf16x8 aq0, aq1;
        {
            const char* qb = smem + QB_OFF + wave * 2304;
            aq0 = *(const bf16x8*)(qb + ln * 144 + g * 16);
            aq1 = *(const bf16x8*)(qb + ln * 144 + 64 + g * 16);
        }

        // ---------------- S = Q * X^T : 16 rows x 512 cols per wave ----------------
        f32x4 accs[32];
        #pragma unroll
        for (int mt = 0; mt < 32; ++mt) {
            const int m = mt * 16 + ln;                // B col = m
            const bf16x8 xb0 = *(const bf16x8*)(smem + XRM_OFF + m * 128 + (((0 + g) ^ (m & 7)) * 16));
            const bf16x8 xb1 = *(const bf16x8*)(smem + XRM_OFF + m * 128 + (((4 + g) ^ (m & 7)) * 16));
            f32x4 t = {0.f,0.f,0.f,0.f};
            t = __builtin_amdgcn_mfma_f32_16x16x32_bf16(aq0, xb0, t, 0, 0, 0);
            t = __builtin_amdgcn_mfma_f32_16x16x32_bf16(aq1, xb1, t, 0, 0, 0);
            accs[mt] = t;
        }

        // ---------------- softmax over m (rows live in 16-lane groups) ----------------
        float mx[4], inv[4];
        #pragma unroll
        for (int r = 0; r < 4; ++r) {
            float m0 = -3.402823466e+38f;
            #pragma unroll
            for (int mt = 0; mt < 32; ++mt) m0 = fmaxf(m0, accs[mt][r]);
            #pragma unroll
            for (int s = 1; s < 16; s <<= 1) m0 = fmaxf(m0, __shfl_xor(m0, s, 64));
            mx[r] = m0;
        }
        #pragma unroll
        for (int r = 0; r < 4; ++r) {
            float s0 = 0.f;
            #pragma unroll
            for (int mt = 0; mt < 32; ++mt) {
                const float e = __expf((accs[mt][r] - mx[r]) * 0.125f);  // scale 1/sqrt(64)
                accs[mt][r] = e;
                s0 += e;
            }
            #pragma unroll
            for (int s = 1; s < 16; s <<= 1) s0 += __shfl_xor(s0, s, 64);
            inv[r] = 1.0f / s0;
        }
        #pragma unroll
        for (int mt = 0; mt < 32; ++mt) {
            #pragma unroll
            for (int r = 0; r < 4; ++r) accs[mt][r] *= inv[r];
        }

        // ---------------- write attn [o,j,b,l,m] fp32, nontemporal ----------------
        {
            const size_t abase = (size_t)((o * 4 + j) * 16 + b) * 262144;
            const int l0 = lt * 128 + wave * 16 + g * 4;
            #pragma unroll
            for (int r = 0; r < 4; ++r) {
                float* rowp = attn_out + abase + (size_t)(l0 + r) * 512 + ln;
                #pragma unroll
                for (int mt = 0; mt < 32; ++mt)
                    __builtin_nontemporal_store(accs[mt][r], rowp + mt * 16);
            }
        }

        // ---------------- ctx += A * X  (m-chunks of 64 via wave-private LDS) ----------------
        {
            char* ach = smem + ACH_OFF + wave * 2304;
            for (int c = 0; c < 8; ++c) {
                #pragma unroll
                for (int t4 = 0; t4 < 4; ++t4) {
                    const int mt = c * 4 + t4;
                    #pragma unroll
                    for (int r = 0; r < 4; ++r)
                        *(unsigned short*)(ach + (g * 4 + r) * 144 + (t4 * 16 + ln) * 2) = f2bf(accs[mt][r]);
                }
                __syncthreads();   // uniform; also orders same-wave LDS write->read
                const bf16x8 pa0 = *(const bf16x8*)(ach + ln * 144 + g * 16);
                const bf16x8 pa1 = *(const bf16x8*)(ach + ln * 144 + 64 + g * 16);
                #pragma unroll
                for (int dt = 0; dt < 4; ++dt) {
                    const int d = dt * 16 + ln;
                    const bf16x8 xb0 = *(const bf16x8*)(smem + XCM_OFF + d * 1040 + c * 128 + g * 16);
                    const bf16x8 xb1 = *(const bf16x8*)(smem + XCM_OFF + d * 1040 + c * 128 + 64 + g * 16);
                    acc_c[dt] = __builtin_amdgcn_mfma_f32_16x16x32_bf16(pa0, xb0, acc_c[dt], 0, 0, 0);
                    acc_c[dt] = __builtin_amdgcn_mfma_f32_16x16x32_bf16(pa1, xb1, acc_c[dt], 0, 0, 0);
                }
            }
        }
    }

    // ---------------- out[b,l,o,d] = 0.25 * sum_j ctx ----------------
    {
        const int l0 = lt * 128 + wave * 16 + g * 4;
        #pragma unroll
        for (int dt = 0; dt < 4; ++dt) {
            #pragma unroll
            for (int r = 0; r < 4; ++r) {
                const int l = l0 + r;
                out[(((size_t)b * 512 + l) * 4 + o) * 64 + dt * 16 + ln] = acc_c[dt][r] * 0.25f;
            }
        }
    }
}

extern "C" void kernel_launch(void* const* d_in, const int* in_sizes, int n_in,
                              void* d_out, int out_size, void* d_ws, size_t ws_size,
                              hipStream_t stream) {
    const float* inp = (const float*)d_in[0];
    const float* Wg  = (const float*)d_in[1];
    float* out = (float*)d_out;

    // 156 KB dynamic LDS (> 64 KB): raise the cap defensively every call (idempotent,
    // host-side, graph-capture safe -- not a stream/alloc/sync op).
    (void)hipFuncSetAttribute((const void*)convattn_kernel,
                              hipFuncAttributeMaxDynamicSharedMemorySize, LDS_BYTES);

    convattn_kernel<<<dim3(256), dim3(512), LDS_BYTES, stream>>>(inp, Wg, out);
}

// Round 2
// 357.348 us; speedup vs baseline: 1.1006x; 1.1006x over previous
//
#include <hip/hip_runtime.h>
#include <stdint.h>

// ConvAttnLayer: B=16, L=512, J=4, O=4, D=E=64.
// out0 = mean_j softmax(X_j W_oj X_j^T / 8) X_j ; out1 = attn (268 MB fp32).
// HBM-write-bound floor ~55 us. Round-1 was latency-bound (all pipes idle):
// 44 barriers/block @ 1 block/CU + 1.1e7 LDS bank conflicts.
//
// Round-2 restructure: each wave computes S^T (X rows = MFMA A, Q^T = B).
//  - softmax: per-lane reg reduction + 2 shfl_xor (column lives in lane&15 group)
//  - C-phase: ctx^T = X^T * E^T; X^T A-frags from swizzled col-major LDS (XCM),
//    E^T B-frags built by 8 bpermute + 4 cndmask per 32-m chunk (no LDS bounce,
//    no barriers). Only 2 __syncthreads per j.
//  - S computed twice (max pass, then exp pass stashing bf16 E in 64 VGPRs).
//  - attn/out stores coalesced to 64B segments via wave-private LDS bounce.

typedef __bf16 bf16x8 __attribute__((ext_vector_type(8)));
typedef float  f32x4  __attribute__((ext_vector_type(4)));
typedef unsigned int u32;
typedef u32 u32x4 __attribute__((ext_vector_type(4)));

#define XRM_OFF 0         // 65536: X row-major bf16, 16B cells XOR (d>>3)^(m&7)
#define XCM_OFF 65536     // 65536: X col-major bf16, 16B cells XOR (m>>3)^((d>>2)&7)
#define WT_OFF  131072    // 9216 : W^T [e][d] stride 144
#define QB_OFF  140288    // 8*2304: per-wave Q bounce (Q phase) / AB bounce (P3+epilogue)
#define LDS_BYTES 158720

static __device__ __forceinline__ u32 f2bf(float f) {
    u32 u = __builtin_bit_cast(u32, f);
    u += 0x7fffu + ((u >> 16) & 1u);   // RNE (finite)
    return u >> 16;
}
static __device__ __forceinline__ float bflo2f(u32 p) { return __builtin_bit_cast(float, p << 16); }
static __device__ __forceinline__ float bfhi2f(u32 p) { return __builtin_bit_cast(float, p & 0xffff0000u); }

__global__ __launch_bounds__(512, 2) void convattn_kernel(
    const float* __restrict__ inp,   // [16,512,4,64]
    const float* __restrict__ Wg,    // [4,4,64,64]
    float* __restrict__ out)         // out0 (2097152) ++ attn (67108864)
{
    extern __shared__ __align__(16) char smem[];
    const int tid  = threadIdx.x;
    const int wave = tid >> 6;
    const int lane = tid & 63;
    const int g    = lane >> 4;     // MFMA k-group
    const int ln   = lane & 15;     // MFMA row/col within tile
    const int rl   = lane >> 2;     // bounce-read row (0..15)
    const int rq   = lane & 3;      // bounce-read quad

    const int bid = blockIdx.x;
    const int b  = bid & 15;        // same-b blocks share an XCD (bid%8 fixed by b)
    const int o  = (bid >> 4) & 3;
    const int lt = bid >> 6;
    const int l0 = lt * 128 + wave * 16;   // this wave's 16 l-columns

    float* attn_out = out + (size_t)2097152;
    char* qb = smem + QB_OFF + wave * 2304;   // wave-private bounce buffer

    f32x4 acc_c[4];
    #pragma unroll
    for (int i = 0; i < 4; ++i) { f32x4 z = {0.f,0.f,0.f,0.f}; acc_c[i] = z; }

    #pragma unroll 1
    for (int j = 0; j < 4; ++j) {
        __syncthreads();   // guard LDS reuse across j

        // ---------------- stage X_j (XRM + XCM) and W^T ----------------
        {
            const int q = tid & 15, p = tid >> 4;
            const int e0 = q << 2;
            #pragma unroll
            for (int it = 0; it < 8; ++it) {
                const int m0 = it * 64 + p * 2;
                const float* src = inp + (((size_t)b * 512 + m0) * 4 + j) * 64 + e0;
                const float4 va = *(const float4*)src;
                const float4 vb = *(const float4*)(src + 256);   // row m0+1
                const u32 pa0 = f2bf(va.x), pa1 = f2bf(va.y), pa2 = f2bf(va.z), pa3 = f2bf(va.w);
                const u32 pb0 = f2bf(vb.x), pb1 = f2bf(vb.y), pb2 = f2bf(vb.z), pb3 = f2bf(vb.w);
                // XRM: b64 per row; cell=(e0>>3)^(m&7); within-cell byte (e0&7)*2
                {
                    uint2 w0; w0.x = pa0 | (pa1 << 16); w0.y = pa2 | (pa3 << 16);
                    *(uint2*)(smem + XRM_OFF + m0 * 128 + (((q >> 1) ^ (m0 & 7)) * 16) + ((q & 1) * 8)) = w0;
                    uint2 w1; w1.x = pb0 | (pb1 << 16); w1.y = pb2 | (pb3 << 16);
                    *(uint2*)(smem + XRM_OFF + (m0 + 1) * 128 + (((q >> 1) ^ ((m0 + 1) & 7)) * 16) + ((q & 1) * 8)) = w1;
                }
                // XCM: pack (m0,m0+1) pairs -> b32; cell=(m>>3)^((d>>2)&7)
                const u32 pc[4] = { pa0 | (pb0 << 16), pa1 | (pb1 << 16),
                                    pa2 | (pb2 << 16), pa3 | (pb3 << 16) };
                #pragma unroll
                for (int c = 0; c < 4; ++c) {
                    const int d = e0 + c;
                    *(u32*)(smem + XCM_OFF + d * 1024 + (((m0 >> 3) ^ ((d >> 2) & 7)) * 16) + (m0 & 7) * 2) = pc[c];
                }
            }
            #pragma unroll
            for (int it = 0; it < 2; ++it) {
                const int d = it * 32 + p;
                const float4 wv = *(const float4*)(Wg + (((size_t)o * 4 + j) * 64 + d) * 64 + e0);
                *(unsigned short*)(smem + WT_OFF + (e0 + 0) * 144 + d * 2) = (unsigned short)f2bf(wv.x);
                *(unsigned short*)(smem + WT_OFF + (e0 + 1) * 144 + d * 2) = (unsigned short)f2bf(wv.y);
                *(unsigned short*)(smem + WT_OFF + (e0 + 2) * 144 + d * 2) = (unsigned short)f2bf(wv.z);
                *(unsigned short*)(smem + WT_OFF + (e0 + 3) * 144 + d * 2) = (unsigned short)f2bf(wv.w);
            }
        }
        __syncthreads();

        // ---------------- Q for this wave's 16 l's; bounce to Q^T B-frags ----------------
        {
            const int lq = l0 + ln;
            const bf16x8 aq0 = *(const bf16x8*)(smem + XRM_OFF + lq * 128 + (((0 + g) ^ (lq & 7)) * 16));
            const bf16x8 aq1 = *(const bf16x8*)(smem + XRM_OFF + lq * 128 + (((4 + g) ^ (lq & 7)) * 16));
            #pragma unroll
            for (int et = 0; et < 4; ++et) {
                const int e = et * 16 + ln;
                const bf16x8 bw0 = *(const bf16x8*)(smem + WT_OFF + e * 144 + g * 16);
                const bf16x8 bw1 = *(const bf16x8*)(smem + WT_OFF + e * 144 + 64 + g * 16);
                f32x4 t = {0.f,0.f,0.f,0.f};
                t = __builtin_amdgcn_mfma_f32_16x16x32_bf16(aq0, bw0, t, 0, 0, 0);
                t = __builtin_amdgcn_mfma_f32_16x16x32_bf16(aq1, bw1, t, 0, 0, 0);
                #pragma unroll
                for (int r = 0; r < 4; ++r)
                    *(unsigned short*)(qb + (g * 4 + r) * 144 + e * 2) = (unsigned short)f2bf(t[r]);
            }
        }
        const bf16x8 bq0 = *(const bf16x8*)(qb + ln * 144 + g * 16);
        const bf16x8 bq1 = *(const bf16x8*)(qb + ln * 144 + 64 + g * 16);

        // ---------------- P1: S^T = X * Q^T, track column max ----------------
        float mx = -3.402823466e+38f;
        #pragma unroll
        for (int mt = 0; mt < 32; ++mt) {
            const int m = mt * 16 + ln;
            const bf16x8 ax0 = *(const bf16x8*)(smem + XRM_OFF + m * 128 + (((0 + g) ^ (m & 7)) * 16));
            const bf16x8 ax1 = *(const bf16x8*)(smem + XRM_OFF + m * 128 + (((4 + g) ^ (m & 7)) * 16));
            f32x4 t = {0.f,0.f,0.f,0.f};
            t = __builtin_amdgcn_mfma_f32_16x16x32_bf16(ax0, bq0, t, 0, 0, 0);
            t = __builtin_amdgcn_mfma_f32_16x16x32_bf16(ax1, bq1, t, 0, 0, 0);
            mx = fmaxf(mx, fmaxf(fmaxf(t[0], t[1]), fmaxf(t[2], t[3])));
        }
        mx = fmaxf(mx, __shfl_xor(mx, 16, 64));
        mx = fmaxf(mx, __shfl_xor(mx, 32, 64));

        // ---------------- P2: recompute S^T, exp, stash bf16 E, column sum ----------------
        float sum = 0.f;
        u32 sLo[32], sHi[32];
        #pragma unroll
        for (int mt = 0; mt < 32; ++mt) {
            const int m = mt * 16 + ln;
            const bf16x8 ax0 = *(const bf16x8*)(smem + XRM_OFF + m * 128 + (((0 + g) ^ (m & 7)) * 16));
            const bf16x8 ax1 = *(const bf16x8*)(smem + XRM_OFF + m * 128 + (((4 + g) ^ (m & 7)) * 16));
            f32x4 t = {0.f,0.f,0.f,0.f};
            t = __builtin_amdgcn_mfma_f32_16x16x32_bf16(ax0, bq0, t, 0, 0, 0);
            t = __builtin_amdgcn_mfma_f32_16x16x32_bf16(ax1, bq1, t, 0, 0, 0);
            const float e0v = __expf((t[0] - mx) * 0.125f);
            const float e1v = __expf((t[1] - mx) * 0.125f);
            const float e2v = __expf((t[2] - mx) * 0.125f);
            const float e3v = __expf((t[3] - mx) * 0.125f);
            sum += (e0v + e1v) + (e2v + e3v);
            sLo[mt] = f2bf(e0v) | (f2bf(e1v) << 16);
            sHi[mt] = f2bf(e2v) | (f2bf(e3v) << 16);
        }
        sum += __shfl_xor(sum, 16, 64);
        sum += __shfl_xor(sum, 32, 64);
        const float inv = 1.0f / sum;

        // ---------------- P3: attn store (bounced) + ctx^T += X^T * E^T ----------------
        const size_t abase = ((size_t)((o * 4 + j) * 16 + b)) * 262144 + (size_t)l0 * 512;
        const int srcLo = ((g & 1) << 5) + ln;
        const int srcHi = srcLo + 16;
        #pragma unroll
        for (int ch = 0; ch < 16; ++ch) {
            u32 pLo[2], pHi[2];
            #pragma unroll
            for (int s = 0; s < 2; ++s) {
                const int mt = ch * 2 + s;
                const float a0v = bflo2f(sLo[mt]) * inv;
                const float a1v = bfhi2f(sLo[mt]) * inv;
                const float a2v = bflo2f(sHi[mt]) * inv;
                const float a3v = bfhi2f(sHi[mt]) * inv;
                // wave-private bounce: AB[l=ln][mloc=4g+r], stride 80
                *(float*)(qb + ln * 80 + (g * 4 + 0) * 4) = a0v;
                *(float*)(qb + ln * 80 + (g * 4 + 1) * 4) = a1v;
                *(float*)(qb + ln * 80 + (g * 4 + 2) * 4) = a2v;
                *(float*)(qb + ln * 80 + (g * 4 + 3) * 4) = a3v;
                const f32x4 rv = *(const f32x4*)(qb + rl * 80 + rq * 16);
                __builtin_nontemporal_store(rv,
                    (f32x4*)(attn_out + abase + (size_t)rl * 512 + mt * 16 + rq * 4));
                pLo[s] = f2bf(a0v) | (f2bf(a1v) << 16);
                pHi[s] = f2bf(a2v) | (f2bf(a3v) << 16);
            }
            // E^T B-frag via cross-lane (g-only moves: same column stays in same ln)
            const u32 a0s = (u32)__shfl((int)pLo[0], srcLo, 64);
            const u32 a1s = (u32)__shfl((int)pHi[0], srcLo, 64);
            const u32 a2s = (u32)__shfl((int)pLo[0], srcHi, 64);
            const u32 a3s = (u32)__shfl((int)pHi[0], srcHi, 64);
            const u32 b0s = (u32)__shfl((int)pLo[1], srcLo, 64);
            const u32 b1s = (u32)__shfl((int)pHi[1], srcLo, 64);
            const u32 b2s = (u32)__shfl((int)pLo[1], srcHi, 64);
            const u32 b3s = (u32)__shfl((int)pHi[1], srcHi, 64);
            const bool hi = (g >= 2);
            const u32 dw0 = hi ? b0s : a0s;
            const u32 dw1 = hi ? b1s : a1s;
            const u32 dw2 = hi ? b2s : a2s;
            const u32 dw3 = hi ? b3s : a3s;
            const bf16x8 bfrag = __builtin_bit_cast(bf16x8, (u32x4){dw0, dw1, dw2, dw3});
            #pragma unroll
            for (int dt = 0; dt < 4; ++dt) {
                const int d = dt * 16 + ln;
                const bf16x8 ax = *(const bf16x8*)(smem + XCM_OFF + d * 1024 +
                                   (((ch * 4 + g) ^ ((d >> 2) & 7)) * 16));
                acc_c[dt] = __builtin_amdgcn_mfma_f32_16x16x32_bf16(ax, bfrag, acc_c[dt], 0, 0, 0);
            }
        }
    }

    // ---------------- epilogue: out[b,l,o,d] = 0.25 * ctx, bounced to float4 ----------------
    #pragma unroll
    for (int dt = 0; dt < 4; ++dt) {
        #pragma unroll
        for (int r = 0; r < 4; ++r)
            *(float*)(qb + ln * 80 + (g * 4 + r) * 4) = acc_c[dt][r] * 0.25f;
        const f32x4 rv = *(const f32x4*)(qb + rl * 80 + rq * 16);
        *(f32x4*)(out + (((size_t)b * 512 + (l0 + rl)) * 4 + o) * 64 + dt * 16 + rq * 4) = rv;
    }
}

extern "C" void kernel_launch(void* const* d_in, const int* in_sizes, int n_in,
                              void* d_out, int out_size, void* d_ws, size_t ws_size,
                              hipStream_t stream) {
    const float* inp = (const float*)d_in[0];
    const float* Wg  = (const float*)d_in[1];
    float* out = (float*)d_out;
    (void)hipFuncSetAttribute((const void*)convattn_kernel,
                              hipFuncAttributeMaxDynamicSharedMemorySize, LDS_BYTES);
    convattn_kernel<<<dim3(256), dim3(512), LDS_BYTES, stream>>>(inp, Wg, out);
}